// Round 1
// baseline (1129.243 us; speedup 1.0000x reference)
//
#include <hip/hip_runtime.h>
#include <stdint.h>

#define BB 16
#define HH 512
#define WW 512
#define HW 262144            // 2^18
#define BHW 4194304          // 16 * 2^18
#define KSEL 262
#define CAP 8192
#define NTHREADS 256
#define NBLK (BHW / NTHREADS)

// ---------- helpers (rn intrinsics to suppress fma contraction in selection-critical math) ----------
__device__ __forceinline__ float img01(float xv) {
    return __fmul_rn(__fadd_rn(xv, 1.0f), 0.5f);
}
__device__ __forceinline__ float luma3(float c0, float c1, float c2) {
    float t = __fadd_rn(__fmul_rn(0.2989f, c0), __fmul_rn(0.587f, c1));
    return __fadd_rn(t, __fmul_rn(0.114f, c2));
}

// ---------- stage 1: per-pixel prep: guidance I and channel-min of imgPatch ----------
__global__ void k_prep(const float* __restrict__ x, float* __restrict__ Ib, float* __restrict__ cm) {
    int idx = blockIdx.x * NTHREADS + threadIdx.x;
    if (idx >= BHW) return;
    int b = idx >> 18;
    int rem = idx & (HW - 1);
    const float* xb = x + (size_t)b * 3 * HW + rem;
    float x0 = xb[0], x1 = xb[HW], x2 = xb[2 * HW];
    float i0 = img01(x0), i1 = img01(x1), i2 = img01(x2);
    cm[idx] = fminf(i0, fminf(i1, i2));
    // guidance = (luma(x) + 1) / 2   (luma on ORIGINAL x, per reference)
    float t = luma3(x0, x1, x2);
    Ib[idx] = __fmul_rn(__fadd_rn(t, 1.0f), 0.5f);
}

// ---------- 15-wide (radius 7) min pool, separable, pad value 1.0 ----------
__global__ void k_rowmin7(const float* __restrict__ in, float* __restrict__ out) {
    int idx = blockIdx.x * NTHREADS + threadIdx.x;
    if (idx >= BHW) return;
    int xx = idx & (WW - 1);
    int rowbase = idx - xx;
    int a0 = xx - 7, a1 = xx + 7;
    bool clip = (a0 < 0) || (a1 > WW - 1);
    if (a0 < 0) a0 = 0;
    if (a1 > WW - 1) a1 = WW - 1;
    float m = 1e30f;
    for (int xi = a0; xi <= a1; ++xi) m = fminf(m, in[rowbase + xi]);
    if (clip) m = fminf(m, 1.0f);
    out[idx] = m;
}

__global__ void k_colmin7(const float* __restrict__ in, float* __restrict__ out, int mode) {
    int idx = blockIdx.x * NTHREADS + threadIdx.x;
    if (idx >= BHW) return;
    int rem = idx & (HW - 1);
    int boff = idx - rem;      // b*HW
    int y = rem >> 9;
    int xx = rem & (WW - 1);
    int a0 = y - 7, a1 = y + 7;
    bool clip = (a0 < 0) || (a1 > HH - 1);
    if (a0 < 0) a0 = 0;
    if (a1 > HH - 1) a1 = HH - 1;
    float m = 1e30f;
    for (int yi = a0; yi <= a1; ++yi) m = fminf(m, in[boff + yi * WW + xx]);
    if (clip) m = fminf(m, 1.0f);
    if (mode) m = __fsub_rn(1.0f, __fmul_rn(0.95f, m));  // trans_raw = 1 - omega*dc
    out[idx] = m;
}

// ---------- top-k threshold: 2-pass 16-bit radix histograms on float bits (all dc >= 0) ----------
__global__ void k_hist1(const float* __restrict__ dc, uint32_t* __restrict__ hist) {
    int idx = blockIdx.x * NTHREADS + threadIdx.x;
    if (idx >= BHW) return;
    int b = idx >> 18;
    uint32_t u = __float_as_uint(dc[idx]);
    atomicAdd(&hist[(b << 16) + (u >> 16)], 1u);
}

__global__ void k_scan1(const uint32_t* __restrict__ hist, uint32_t* h_star, uint32_t* k1o) {
    int b = blockIdx.x, t = threadIdx.x;
    __shared__ uint32_t s[256];
    __shared__ uint32_t bins[256];
    __shared__ int ci_sh;
    __shared__ uint32_t cum_sh;
    const uint32_t* hb = hist + ((size_t)b << 16);
    uint32_t sum = 0;
    for (int i = 0; i < 256; ++i) sum += hb[t * 256 + i];
    s[t] = sum;
    __syncthreads();
    if (t == 0) {
        uint32_t cum = 0;
        int ci = 0;
        for (int c = 255; c >= 0; --c) {
            if (cum + s[c] >= KSEL) { ci = c; break; }
            cum += s[c];
        }
        ci_sh = ci; cum_sh = cum;
    }
    __syncthreads();
    bins[t] = hb[ci_sh * 256 + t];
    __syncthreads();
    if (t == 0) {
        uint32_t cum = cum_sh, hs = 0, kk = 1;
        for (int i = 255; i >= 0; --i) {
            uint32_t c = bins[i];
            if (cum + c >= KSEL) { hs = (uint32_t)(ci_sh * 256 + i); kk = KSEL - cum; break; }
            cum += c;
        }
        h_star[b] = hs; k1o[b] = kk;
    }
}

__global__ void k_hist2(const float* __restrict__ dc, const uint32_t* __restrict__ h_star,
                        uint32_t* __restrict__ hist) {
    int idx = blockIdx.x * NTHREADS + threadIdx.x;
    if (idx >= BHW) return;
    int b = idx >> 18;
    uint32_t u = __float_as_uint(dc[idx]);
    if ((u >> 16) == h_star[b]) atomicAdd(&hist[(b << 16) + (u & 0xFFFFu)], 1u);
}

__global__ void k_scan2(const uint32_t* __restrict__ hist, const uint32_t* __restrict__ h_star,
                        const uint32_t* __restrict__ k1i, uint32_t* vbits, uint32_t* rsel) {
    int b = blockIdx.x, t = threadIdx.x;
    __shared__ uint32_t s[256];
    __shared__ uint32_t bins[256];
    __shared__ int ci_sh;
    __shared__ uint32_t cum_sh;
    const uint32_t* hb = hist + ((size_t)b << 16);
    uint32_t target = k1i[b];
    uint32_t sum = 0;
    for (int i = 0; i < 256; ++i) sum += hb[t * 256 + i];
    s[t] = sum;
    __syncthreads();
    if (t == 0) {
        uint32_t cum = 0;
        int ci = 0;
        for (int c = 255; c >= 0; --c) {
            if (cum + s[c] >= target) { ci = c; break; }
            cum += s[c];
        }
        ci_sh = ci; cum_sh = cum;
    }
    __syncthreads();
    bins[t] = hb[ci_sh * 256 + t];
    __syncthreads();
    if (t == 0) {
        uint32_t cum = cum_sh;
        uint32_t lo = 0, r = 1;
        for (int i = 255; i >= 0; --i) {
            uint32_t c = bins[i];
            if (cum + c >= target) { lo = (uint32_t)(ci_sh * 256 + i); r = target - cum; break; }
            cum += c;
        }
        vbits[b] = (h_star[b] << 16) | lo;
        rsel[b] = r;   // number of ties (dc == v) to include, by smallest index
    }
}

// ---------- collect: best of strict-greater set (packed atomicMax), gather ties ----------
__global__ void k_collect(const float* __restrict__ dc, const float* __restrict__ x,
                          const uint32_t* __restrict__ vbits, unsigned long long* __restrict__ gt,
                          uint32_t* __restrict__ tiecnt, uint32_t* __restrict__ ties) {
    int idx = blockIdx.x * NTHREADS + threadIdx.x;
    if (idx >= BHW) return;
    int b = idx >> 18;
    int rem = idx & (HW - 1);
    uint32_t u = __float_as_uint(dc[idx]);
    uint32_t v = vbits[b];
    if (u < v) return;
    if (u > v) {
        const float* xb = x + (size_t)b * 3 * HW + rem;
        float i0 = img01(xb[0]), i1 = img01(xb[HW]), i2 = img01(xb[2 * HW]);
        float inten = luma3(i0, i1, i2);   // intensity on imgPatch (per reference)
        unsigned long long packed =
            ((unsigned long long)__float_as_uint(inten) << 32) | (uint32_t)(0xFFFFFFFFu - (uint32_t)rem);
        atomicMax(&gt[b], packed);
    } else {
        uint32_t pos = atomicAdd(&tiecnt[b], 1u);
        if (pos < CAP) ties[(size_t)b * CAP + pos] = (uint32_t)rem;
    }
}

// ---------- select: rank ties by index, take r smallest, argmax intensity; produce A ----------
__global__ void k_select(const float* __restrict__ x, const uint32_t* __restrict__ rsel,
                         const unsigned long long* __restrict__ gt, const uint32_t* __restrict__ tiecnt,
                         const uint32_t* __restrict__ ties, float* __restrict__ mapA3,
                         float* __restrict__ Ap3) {
    int b = blockIdx.x, t = threadIdx.x;
    __shared__ uint32_t tl[CAP];
    __shared__ unsigned long long red[256];
    uint32_t n = tiecnt[b];
    if (n > CAP) n = CAP;
    uint32_t r = rsel[b];
    const uint32_t* tb = ties + (size_t)b * CAP;
    for (uint32_t i = t; i < n; i += 256) tl[i] = tb[i];
    __syncthreads();
    unsigned long long best = 0;
    for (uint32_t i = t; i < n; i += 256) {
        uint32_t myidx = tl[i];
        uint32_t rank = 0;
        for (uint32_t j = 0; j < n; ++j) rank += (tl[j] < myidx) ? 1u : 0u;
        if (rank < r) {
            const float* xb = x + (size_t)b * 3 * HW + myidx;
            float i0 = img01(xb[0]), i1 = img01(xb[HW]), i2 = img01(xb[2 * HW]);
            float inten = luma3(i0, i1, i2);
            unsigned long long packed =
                ((unsigned long long)__float_as_uint(inten) << 32) | (uint32_t)(0xFFFFFFFFu - myidx);
            if (packed > best) best = packed;
        }
    }
    red[t] = best;
    __syncthreads();
    for (int s2 = 128; s2 > 0; s2 >>= 1) {
        if (t < s2) red[t] = (red[t] > red[t + s2]) ? red[t] : red[t + s2];
        __syncthreads();
    }
    if (t == 0) {
        unsigned long long tie = red[0], g = gt[b];
        // gt pixels come first in top_k order; equal intensity -> gt wins (first occurrence)
        unsigned long long fin = ((g >> 32) >= (tie >> 32)) ? g : tie;
        if (g == 0ull) fin = tie;   // no strict-greater pixels at all
        uint32_t rem = 0xFFFFFFFFu - (uint32_t)(fin & 0xFFFFFFFFull);
        const float* xb = x + (size_t)b * 3 * HW + rem;
        for (int c = 0; c < 3; ++c) {
            float A = img01(xb[c * HW]);                      // imgPatch value
            float mA = __fsub_rn(__fmul_rn(A, 2.0f), 1.0f);   // map_A = A*2-1
            float Ap = __fmul_rn(__fadd_rn(mA, 1.0f), 0.5f);  // (map_A+1)/2 (exactly as reference)
            mapA3[b * 3 + c] = mA;
            Ap3[b * 3 + c] = Ap;
        }
    }
}

// ---------- second dark channel input: min_c( imgPatch_c / Ap_c ) ----------
__global__ void k_cmin2(const float* __restrict__ x, const float* __restrict__ Ap3,
                        float* __restrict__ cm) {
    int idx = blockIdx.x * NTHREADS + threadIdx.x;
    if (idx >= BHW) return;
    int b = idx >> 18;
    int rem = idx & (HW - 1);
    const float* xb = x + (size_t)b * 3 * HW + rem;
    float v0 = __fdiv_rn(img01(xb[0]), Ap3[b * 3 + 0]);
    float v1 = __fdiv_rn(img01(xb[HW]), Ap3[b * 3 + 1]);
    float v2 = __fdiv_rn(img01(xb[2 * HW]), Ap3[b * 3 + 2]);
    cm[idx] = fminf(v0, fminf(v1, v2));
}

// ---------- 31-wide (radius 15) box sums, separable, zero pad (sum valid only) ----------
__global__ void k_rowsum4(const float* __restrict__ I, const float* __restrict__ p,
                          float* __restrict__ rs) {
    int idx = blockIdx.x * NTHREADS + threadIdx.x;
    if (idx >= BHW) return;
    int xx = idx & (WW - 1);
    int rowbase = idx - xx;
    int a0 = xx - 15, a1 = xx + 15;
    if (a0 < 0) a0 = 0;
    if (a1 > WW - 1) a1 = WW - 1;
    float sI = 0.f, sP = 0.f, sIP = 0.f, sII = 0.f;
    for (int xi = a0; xi <= a1; ++xi) {
        float iv = I[rowbase + xi];
        float pv = p[rowbase + xi];
        sI += iv; sP += pv; sIP += iv * pv; sII += iv * iv;
    }
    rs[idx] = sI;
    rs[(size_t)BHW + idx] = sP;
    rs[(size_t)2 * BHW + idx] = sIP;
    rs[(size_t)3 * BHW + idx] = sII;
}

__global__ void k_colsum_ab(const float* __restrict__ rs, float* __restrict__ aout,
                            float* __restrict__ bout) {
    int idx = blockIdx.x * NTHREADS + threadIdx.x;
    if (idx >= BHW) return;
    int rem = idx & (HW - 1);
    int boff = idx - rem;
    int y = rem >> 9;
    int xx = rem & (WW - 1);
    int a0 = y - 15, a1 = y + 15;
    if (a0 < 0) a0 = 0;
    if (a1 > HH - 1) a1 = HH - 1;
    const float* rI = rs;
    const float* rP = rs + (size_t)BHW;
    const float* rIP = rs + (size_t)2 * BHW;
    const float* rII = rs + (size_t)3 * BHW;
    float sI = 0.f, sP = 0.f, sIP = 0.f, sII = 0.f;
    for (int yi = a0; yi <= a1; ++yi) {
        int o = boff + yi * WW + xx;
        sI += rI[o]; sP += rP[o]; sIP += rIP[o]; sII += rII[o];
    }
    int ny = a1 - a0 + 1;
    int x0 = xx - 15, x1 = xx + 15;
    if (x0 < 0) x0 = 0;
    if (x1 > WW - 1) x1 = WW - 1;
    float N = (float)(ny * (x1 - x0 + 1));
    float mI = sI / N, mP = sP / N, mIP = sIP / N, mII = sII / N;
    float cov = mIP - mI * mP;
    float var = mII - mI * mI;
    float a = cov / (var + 1e-3f);
    float bb = mP - a * mI;
    aout[idx] = a;
    bout[idx] = bb;
}

__global__ void k_rowsum2(const float* __restrict__ a, const float* __restrict__ b,
                          float* __restrict__ ra, float* __restrict__ rb) {
    int idx = blockIdx.x * NTHREADS + threadIdx.x;
    if (idx >= BHW) return;
    int xx = idx & (WW - 1);
    int rowbase = idx - xx;
    int a0 = xx - 15, a1 = xx + 15;
    if (a0 < 0) a0 = 0;
    if (a1 > WW - 1) a1 = WW - 1;
    float sa = 0.f, sb = 0.f;
    for (int xi = a0; xi <= a1; ++xi) {
        sa += a[rowbase + xi];
        sb += b[rowbase + xi];
    }
    ra[idx] = sa;
    rb[idx] = sb;
}

__global__ void k_final(const float* __restrict__ ra, const float* __restrict__ rb,
                        const float* __restrict__ Ib, const float* __restrict__ x,
                        const float* __restrict__ mapA3, float* __restrict__ out) {
    int idx = blockIdx.x * NTHREADS + threadIdx.x;
    if (idx >= BHW) return;
    int rem = idx & (HW - 1);
    int b = idx >> 18;
    int boff = idx - rem;
    int y = rem >> 9;
    int xx = rem & (WW - 1);
    int a0 = y - 15, a1 = y + 15;
    if (a0 < 0) a0 = 0;
    if (a1 > HH - 1) a1 = HH - 1;
    float Sa = 0.f, Sb = 0.f;
    for (int yi = a0; yi <= a1; ++yi) {
        int o = boff + yi * WW + xx;
        Sa += ra[o];
        Sb += rb[o];
    }
    int ny = a1 - a0 + 1;
    int x0 = xx - 15, x1 = xx + 15;
    if (x0 < 0) x0 = 0;
    if (x1 > WW - 1) x1 = WW - 1;
    float N = (float)(ny * (x1 - x0 + 1));
    float ma = Sa / N, mb = Sb / N;
    float Iv = Ib[idx];
    float T = ma * Iv + mb;
    out[(size_t)3 * BHW + idx] = T;   // T_DCP region
    const float* xb = x + (size_t)b * 3 * HW + rem;
    for (int c = 0; c < 3; ++c) {
        float mA = mapA3[b * 3 + c];
        float img = img01(xb[c * HW]);
        float J = (img - mA) / T + mA;
        out[(size_t)(b * 3 + c) * HW + rem] = J;                       // J_DCP region
        out[(size_t)4 * BHW + (size_t)(b * 3 + c) * HW + rem] = mA;    // map_A region
    }
}

extern "C" void kernel_launch(void* const* d_in, const int* in_sizes, int n_in,
                              void* d_out, int out_size, void* d_ws, size_t ws_size,
                              hipStream_t stream) {
    const float* x = (const float*)d_in[0];
    float* out = (float*)d_out;
    char* ws = (char*)d_ws;

    // workspace layout (floats)
    float* Ib   = (float*)ws;                 // guidance I          [BHW]
    float* pb   = Ib + (size_t)BHW;           // trans_raw p / rb    [BHW]
    float* bufA = Ib + (size_t)2 * BHW;       // cmin / a            [BHW]
    float* bufB = Ib + (size_t)3 * BHW;       // rowmin tmp / b      [BHW]
    float* bufC = Ib + (size_t)4 * BHW;       // dc / ra             [BHW]
    uint32_t* hist = (uint32_t*)(ws + (size_t)5 * BHW * 4);          // 16*65536 u32 = 4MB
    char* small = ws + (size_t)5 * BHW * 4 + (size_t)16 * 65536 * 4;
    uint32_t* h_star = (uint32_t*)(small + 0);
    uint32_t* k1     = (uint32_t*)(small + 64);
    uint32_t* vbits  = (uint32_t*)(small + 128);
    uint32_t* rsel   = (uint32_t*)(small + 192);
    uint32_t* tiecnt = (uint32_t*)(small + 256);
    unsigned long long* gt = (unsigned long long*)(small + 320);
    float* mapA3 = (float*)(small + 448);
    float* Ap3   = (float*)(small + 640);
    uint32_t* ties = (uint32_t*)(small + 1024);   // 16*CAP u32 = 512KB
    float* rs = out;   // reuse first 4*BHW floats of d_out as row-sum scratch (overwritten at the end)

    dim3 blk(NTHREADS), grid(NBLK);

    // dark channel of imgPatch
    k_prep<<<grid, blk, 0, stream>>>(x, Ib, bufA);
    k_rowmin7<<<grid, blk, 0, stream>>>(bufA, bufB);
    k_colmin7<<<grid, blk, 0, stream>>>(bufB, bufC, 0);

    // exact top-k threshold (k-th largest dc value v, tie count r)
    hipMemsetAsync(hist, 0, (size_t)16 * 65536 * 4, stream);
    k_hist1<<<grid, blk, 0, stream>>>(bufC, hist);
    k_scan1<<<16, 256, 0, stream>>>(hist, h_star, k1);
    hipMemsetAsync(hist, 0, (size_t)16 * 65536 * 4, stream);
    k_hist2<<<grid, blk, 0, stream>>>(bufC, h_star, hist);
    k_scan2<<<16, 256, 0, stream>>>(hist, h_star, k1, vbits, rsel);

    // atmospheric light selection
    hipMemsetAsync(tiecnt, 0, 64, stream);
    hipMemsetAsync(gt, 0, 128, stream);
    k_collect<<<grid, blk, 0, stream>>>(bufC, x, vbits, gt, tiecnt, ties);
    k_select<<<16, 256, 0, stream>>>(x, rsel, gt, tiecnt, ties, mapA3, Ap3);

    // transmission raw = 1 - 0.95 * darkchannel(imgPatch / A)
    k_cmin2<<<grid, blk, 0, stream>>>(x, Ap3, bufA);
    k_rowmin7<<<grid, blk, 0, stream>>>(bufA, bufB);
    k_colmin7<<<grid, blk, 0, stream>>>(bufB, pb, 1);

    // guided filter (r=15, eps=1e-3)
    k_rowsum4<<<grid, blk, 0, stream>>>(Ib, pb, rs);
    k_colsum_ab<<<grid, blk, 0, stream>>>(rs, bufA, bufB);
    k_rowsum2<<<grid, blk, 0, stream>>>(bufA, bufB, bufC, pb);
    k_final<<<grid, blk, 0, stream>>>(bufC, pb, Ib, x, mapA3, out);
}

// Round 2
// 553.039 us; speedup vs baseline: 2.0419x; 2.0419x over previous
//
#include <hip/hip_runtime.h>
#include <stdint.h>

#define BB 16
#define HH 512
#define WW 512
#define HW 262144            // 2^18
#define BHW 4194304          // 16 * 2^18
#define KSEL 262
#define CAP 8192
#define NTHREADS 256
#define NBLK (BHW / NTHREADS)
#define BLKPB 64             // radix blocks per batch
#define CHUNK (HW / BLKPB)   // 4096 pixels per radix block

// ---------- helpers (rn intrinsics to suppress fma contraction in selection-critical math) ----------
__device__ __forceinline__ float img01(float xv) {
    return __fmul_rn(__fadd_rn(xv, 1.0f), 0.5f);
}
__device__ __forceinline__ float luma3(float c0, float c1, float c2) {
    float t = __fadd_rn(__fmul_rn(0.2989f, c0), __fmul_rn(0.587f, c1));
    return __fadd_rn(t, __fmul_rn(0.114f, c2));
}

// ---------- stage 1: per-pixel prep: guidance I and channel-min of imgPatch ----------
__global__ void k_prep(const float* __restrict__ x, float* __restrict__ Ib, float* __restrict__ cm) {
    int idx = blockIdx.x * NTHREADS + threadIdx.x;
    if (idx >= BHW) return;
    int b = idx >> 18;
    int rem = idx & (HW - 1);
    const float* xb = x + (size_t)b * 3 * HW + rem;
    float x0 = xb[0], x1 = xb[HW], x2 = xb[2 * HW];
    float i0 = img01(x0), i1 = img01(x1), i2 = img01(x2);
    cm[idx] = fminf(i0, fminf(i1, i2));
    float t = luma3(x0, x1, x2);
    Ib[idx] = __fmul_rn(__fadd_rn(t, 1.0f), 0.5f);
}

// ---------- 15-wide (radius 7) min pool, separable, pad value 1.0 ----------
__global__ void k_rowmin7(const float* __restrict__ in, float* __restrict__ out) {
    int idx = blockIdx.x * NTHREADS + threadIdx.x;
    if (idx >= BHW) return;
    int xx = idx & (WW - 1);
    int rowbase = idx - xx;
    int a0 = xx - 7, a1 = xx + 7;
    bool clip = (a0 < 0) || (a1 > WW - 1);
    if (a0 < 0) a0 = 0;
    if (a1 > WW - 1) a1 = WW - 1;
    float m = 1e30f;
    for (int xi = a0; xi <= a1; ++xi) m = fminf(m, in[rowbase + xi]);
    if (clip) m = fminf(m, 1.0f);
    out[idx] = m;
}

__global__ void k_colmin7(const float* __restrict__ in, float* __restrict__ out, int mode) {
    int idx = blockIdx.x * NTHREADS + threadIdx.x;
    if (idx >= BHW) return;
    int rem = idx & (HW - 1);
    int boff = idx - rem;      // b*HW
    int y = rem >> 9;
    int xx = rem & (WW - 1);
    int a0 = y - 7, a1 = y + 7;
    bool clip = (a0 < 0) || (a1 > HH - 1);
    if (a0 < 0) a0 = 0;
    if (a1 > HH - 1) a1 = HH - 1;
    float m = 1e30f;
    for (int yi = a0; yi <= a1; ++yi) m = fminf(m, in[boff + yi * WW + xx]);
    if (clip) m = fminf(m, 1.0f);
    if (mode) m = __fsub_rn(1.0f, __fmul_rn(0.95f, m));  // trans_raw = 1 - omega*dc
    out[idx] = m;
}

// ---------- exact top-k via 4x8-bit radix select, LDS-privatized histograms ----------
// state[b] = { prefix_bits, remaining_target }. After 4 passes:
//   state[b].x = float bits of k-th largest dc value v
//   state[b].y = r = number of ties (dc == v) to include (by smallest index)
__global__ void k_init(uint2* __restrict__ state, uint32_t* __restrict__ hist256,
                       uint32_t* __restrict__ tiecnt, unsigned long long* __restrict__ gt) {
    int t = blockIdx.x * 256 + threadIdx.x;
    if (t < 16 * 256) hist256[t] = 0;
    if (t < 16) {
        state[t] = make_uint2(0u, KSEL);
        tiecnt[t] = 0;
        gt[t] = 0ull;
    }
}

__global__ void k_radix_pass(const float* __restrict__ dc, const uint2* __restrict__ state,
                             uint32_t* __restrict__ hist256, int shift) {
    __shared__ uint32_t h[256];
    int b = blockIdx.x / BLKPB;
    int blk = blockIdx.x % BLKPB;
    h[threadIdx.x] = 0;
    __syncthreads();
    uint32_t pref = state[b].x;
    uint32_t maskhi = (shift == 24) ? 0u : (0xFFFFFFFFu << (shift + 8));
    const float* d = dc + (size_t)b * HW;
    int base = blk * CHUNK;
    for (int i = base + threadIdx.x; i < base + CHUNK; i += 256) {
        uint32_t u = __float_as_uint(d[i]);
        if ((u & maskhi) == pref) atomicAdd(&h[(u >> shift) & 0xFFu], 1u);
    }
    __syncthreads();
    uint32_t c = h[threadIdx.x];
    if (c) atomicAdd(&hist256[b * 256 + threadIdx.x], c);
}

__global__ void k_radix_scan(uint32_t* __restrict__ hist256, uint2* __restrict__ state, int shift) {
    int b = blockIdx.x, t = threadIdx.x;
    __shared__ uint32_t h[256];
    h[t] = hist256[b * 256 + t];
    __syncthreads();
    hist256[b * 256 + t] = 0;   // ready for next pass
    if (t == 0) {
        uint32_t target = state[b].y;
        uint32_t cum = 0, digit = 0;
        for (int i = 255; i >= 0; --i) {
            uint32_t c = h[i];
            if (cum + c >= target) { digit = (uint32_t)i; target -= cum; break; }
            cum += c;
        }
        state[b].x |= digit << shift;
        state[b].y = target;
    }
}

// ---------- collect: best of strict-greater set (packed atomicMax), gather ties ----------
__global__ void k_collect(const float* __restrict__ dc, const float* __restrict__ x,
                          const uint2* __restrict__ state, unsigned long long* __restrict__ gt,
                          uint32_t* __restrict__ tiecnt, uint32_t* __restrict__ ties) {
    int idx = blockIdx.x * NTHREADS + threadIdx.x;
    if (idx >= BHW) return;
    int b = idx >> 18;
    int rem = idx & (HW - 1);
    uint32_t u = __float_as_uint(dc[idx]);
    uint32_t v = state[b].x;
    if (u < v) return;
    if (u > v) {
        const float* xb = x + (size_t)b * 3 * HW + rem;
        float i0 = img01(xb[0]), i1 = img01(xb[HW]), i2 = img01(xb[2 * HW]);
        float inten = luma3(i0, i1, i2);   // intensity on imgPatch (per reference)
        unsigned long long packed =
            ((unsigned long long)__float_as_uint(inten) << 32) | (uint32_t)(0xFFFFFFFFu - (uint32_t)rem);
        atomicMax(&gt[b], packed);
    } else {
        uint32_t pos = atomicAdd(&tiecnt[b], 1u);
        if (pos < CAP) ties[(size_t)b * CAP + pos] = (uint32_t)rem;
    }
}

// ---------- select: rank ties by index, take r smallest, argmax intensity; produce A ----------
__global__ void k_select(const float* __restrict__ x, const uint2* __restrict__ state,
                         const unsigned long long* __restrict__ gt, const uint32_t* __restrict__ tiecnt,
                         const uint32_t* __restrict__ ties, float* __restrict__ mapA3,
                         float* __restrict__ Ap3) {
    int b = blockIdx.x, t = threadIdx.x;
    __shared__ uint32_t tl[CAP];
    __shared__ unsigned long long red[256];
    uint32_t n = tiecnt[b];
    if (n > CAP) n = CAP;
    uint32_t r = state[b].y;
    const uint32_t* tb = ties + (size_t)b * CAP;
    for (uint32_t i = t; i < n; i += 256) tl[i] = tb[i];
    __syncthreads();
    unsigned long long best = 0;
    for (uint32_t i = t; i < n; i += 256) {
        uint32_t myidx = tl[i];
        uint32_t rank = 0;
        for (uint32_t j = 0; j < n; ++j) rank += (tl[j] < myidx) ? 1u : 0u;
        if (rank < r) {
            const float* xb = x + (size_t)b * 3 * HW + myidx;
            float i0 = img01(xb[0]), i1 = img01(xb[HW]), i2 = img01(xb[2 * HW]);
            float inten = luma3(i0, i1, i2);
            unsigned long long packed =
                ((unsigned long long)__float_as_uint(inten) << 32) | (uint32_t)(0xFFFFFFFFu - myidx);
            if (packed > best) best = packed;
        }
    }
    red[t] = best;
    __syncthreads();
    for (int s2 = 128; s2 > 0; s2 >>= 1) {
        if (t < s2) red[t] = (red[t] > red[t + s2]) ? red[t] : red[t + s2];
        __syncthreads();
    }
    if (t == 0) {
        unsigned long long tie = red[0], g = gt[b];
        unsigned long long fin = ((g >> 32) >= (tie >> 32)) ? g : tie;
        if (g == 0ull) fin = tie;   // no strict-greater pixels at all
        uint32_t rem = 0xFFFFFFFFu - (uint32_t)(fin & 0xFFFFFFFFull);
        const float* xb = x + (size_t)b * 3 * HW + rem;
        for (int c = 0; c < 3; ++c) {
            float A = img01(xb[c * HW]);                      // imgPatch value
            float mA = __fsub_rn(__fmul_rn(A, 2.0f), 1.0f);   // map_A = A*2-1
            float Ap = __fmul_rn(__fadd_rn(mA, 1.0f), 0.5f);  // (map_A+1)/2 (exactly as reference)
            mapA3[b * 3 + c] = mA;
            Ap3[b * 3 + c] = Ap;
        }
    }
}

// ---------- second dark channel input: min_c( imgPatch_c / Ap_c ) ----------
__global__ void k_cmin2(const float* __restrict__ x, const float* __restrict__ Ap3,
                        float* __restrict__ cm) {
    int idx = blockIdx.x * NTHREADS + threadIdx.x;
    if (idx >= BHW) return;
    int b = idx >> 18;
    int rem = idx & (HW - 1);
    const float* xb = x + (size_t)b * 3 * HW + rem;
    float v0 = __fdiv_rn(img01(xb[0]), Ap3[b * 3 + 0]);
    float v1 = __fdiv_rn(img01(xb[HW]), Ap3[b * 3 + 1]);
    float v2 = __fdiv_rn(img01(xb[2 * HW]), Ap3[b * 3 + 2]);
    cm[idx] = fminf(v0, fminf(v1, v2));
}

// ---------- 31-wide (radius 15) box sums, separable, zero pad (sum valid only) ----------
__global__ void k_rowsum4(const float* __restrict__ I, const float* __restrict__ p,
                          float* __restrict__ rs) {
    int idx = blockIdx.x * NTHREADS + threadIdx.x;
    if (idx >= BHW) return;
    int xx = idx & (WW - 1);
    int rowbase = idx - xx;
    int a0 = xx - 15, a1 = xx + 15;
    if (a0 < 0) a0 = 0;
    if (a1 > WW - 1) a1 = WW - 1;
    float sI = 0.f, sP = 0.f, sIP = 0.f, sII = 0.f;
    for (int xi = a0; xi <= a1; ++xi) {
        float iv = I[rowbase + xi];
        float pv = p[rowbase + xi];
        sI += iv; sP += pv; sIP += iv * pv; sII += iv * iv;
    }
    rs[idx] = sI;
    rs[(size_t)BHW + idx] = sP;
    rs[(size_t)2 * BHW + idx] = sIP;
    rs[(size_t)3 * BHW + idx] = sII;
}

__global__ void k_colsum_ab(const float* __restrict__ rs, float* __restrict__ aout,
                            float* __restrict__ bout) {
    int idx = blockIdx.x * NTHREADS + threadIdx.x;
    if (idx >= BHW) return;
    int rem = idx & (HW - 1);
    int boff = idx - rem;
    int y = rem >> 9;
    int xx = rem & (WW - 1);
    int a0 = y - 15, a1 = y + 15;
    if (a0 < 0) a0 = 0;
    if (a1 > HH - 1) a1 = HH - 1;
    const float* rI = rs;
    const float* rP = rs + (size_t)BHW;
    const float* rIP = rs + (size_t)2 * BHW;
    const float* rII = rs + (size_t)3 * BHW;
    float sI = 0.f, sP = 0.f, sIP = 0.f, sII = 0.f;
    for (int yi = a0; yi <= a1; ++yi) {
        int o = boff + yi * WW + xx;
        sI += rI[o]; sP += rP[o]; sIP += rIP[o]; sII += rII[o];
    }
    int ny = a1 - a0 + 1;
    int x0 = xx - 15, x1 = xx + 15;
    if (x0 < 0) x0 = 0;
    if (x1 > WW - 1) x1 = WW - 1;
    float N = (float)(ny * (x1 - x0 + 1));
    float mI = sI / N, mP = sP / N, mIP = sIP / N, mII = sII / N;
    float cov = mIP - mI * mP;
    float var = mII - mI * mI;
    float a = cov / (var + 1e-3f);
    float bb = mP - a * mI;
    aout[idx] = a;
    bout[idx] = bb;
}

__global__ void k_rowsum2(const float* __restrict__ a, const float* __restrict__ b,
                          float* __restrict__ ra, float* __restrict__ rb) {
    int idx = blockIdx.x * NTHREADS + threadIdx.x;
    if (idx >= BHW) return;
    int xx = idx & (WW - 1);
    int rowbase = idx - xx;
    int a0 = xx - 15, a1 = xx + 15;
    if (a0 < 0) a0 = 0;
    if (a1 > WW - 1) a1 = WW - 1;
    float sa = 0.f, sb = 0.f;
    for (int xi = a0; xi <= a1; ++xi) {
        sa += a[rowbase + xi];
        sb += b[rowbase + xi];
    }
    ra[idx] = sa;
    rb[idx] = sb;
}

__global__ void k_final(const float* __restrict__ ra, const float* __restrict__ rb,
                        const float* __restrict__ Ib, const float* __restrict__ x,
                        const float* __restrict__ mapA3, float* __restrict__ out) {
    int idx = blockIdx.x * NTHREADS + threadIdx.x;
    if (idx >= BHW) return;
    int rem = idx & (HW - 1);
    int b = idx >> 18;
    int boff = idx - rem;
    int y = rem >> 9;
    int xx = rem & (WW - 1);
    int a0 = y - 15, a1 = y + 15;
    if (a0 < 0) a0 = 0;
    if (a1 > HH - 1) a1 = HH - 1;
    float Sa = 0.f, Sb = 0.f;
    for (int yi = a0; yi <= a1; ++yi) {
        int o = boff + yi * WW + xx;
        Sa += ra[o];
        Sb += rb[o];
    }
    int ny = a1 - a0 + 1;
    int x0 = xx - 15, x1 = xx + 15;
    if (x0 < 0) x0 = 0;
    if (x1 > WW - 1) x1 = WW - 1;
    float N = (float)(ny * (x1 - x0 + 1));
    float ma = Sa / N, mb = Sb / N;
    float Iv = Ib[idx];
    float T = ma * Iv + mb;
    out[(size_t)3 * BHW + idx] = T;   // T_DCP region
    const float* xb = x + (size_t)b * 3 * HW + rem;
    for (int c = 0; c < 3; ++c) {
        float mA = mapA3[b * 3 + c];
        float img = img01(xb[c * HW]);
        float J = (img - mA) / T + mA;
        out[(size_t)(b * 3 + c) * HW + rem] = J;                       // J_DCP region
        out[(size_t)4 * BHW + (size_t)(b * 3 + c) * HW + rem] = mA;    // map_A region
    }
}

extern "C" void kernel_launch(void* const* d_in, const int* in_sizes, int n_in,
                              void* d_out, int out_size, void* d_ws, size_t ws_size,
                              hipStream_t stream) {
    const float* x = (const float*)d_in[0];
    float* out = (float*)d_out;
    char* ws = (char*)d_ws;

    // workspace layout (floats)
    float* Ib   = (float*)ws;                 // guidance I          [BHW]
    float* pb   = Ib + (size_t)BHW;           // trans_raw p / rb    [BHW]
    float* bufA = Ib + (size_t)2 * BHW;       // cmin / a            [BHW]
    float* bufB = Ib + (size_t)3 * BHW;       // rowmin tmp / b      [BHW]
    float* bufC = Ib + (size_t)4 * BHW;       // dc / ra             [BHW]
    char* small = ws + (size_t)5 * BHW * 4;
    uint2* state = (uint2*)(small + 0);                   // 16 * 8B
    uint32_t* tiecnt = (uint32_t*)(small + 256);          // 16 * 4B
    unsigned long long* gt = (unsigned long long*)(small + 384);  // 16 * 8B
    float* mapA3 = (float*)(small + 512);
    float* Ap3   = (float*)(small + 768);
    uint32_t* hist256 = (uint32_t*)(small + 1024);        // 16*256 u32 = 16KB
    uint32_t* ties = (uint32_t*)(small + 1024 + 16 * 256 * 4);   // 16*CAP u32 = 512KB
    float* rs = out;   // reuse first 4*BHW floats of d_out as row-sum scratch (overwritten at the end)

    dim3 blk(NTHREADS), grid(NBLK);

    // dark channel of imgPatch
    k_prep<<<grid, blk, 0, stream>>>(x, Ib, bufA);
    k_rowmin7<<<grid, blk, 0, stream>>>(bufA, bufB);
    k_colmin7<<<grid, blk, 0, stream>>>(bufB, bufC, 0);

    // exact top-k: k-th largest dc value v + tie count r, via 4x8-bit radix select
    k_init<<<16, 256, 0, stream>>>(state, hist256, tiecnt, gt);
    for (int shift = 24; shift >= 0; shift -= 8) {
        k_radix_pass<<<16 * BLKPB, 256, 0, stream>>>(bufC, state, hist256, shift);
        k_radix_scan<<<16, 256, 0, stream>>>(hist256, state, shift);
    }

    // atmospheric light selection
    k_collect<<<grid, blk, 0, stream>>>(bufC, x, state, gt, tiecnt, ties);
    k_select<<<16, 256, 0, stream>>>(x, state, gt, tiecnt, ties, mapA3, Ap3);

    // transmission raw = 1 - 0.95 * darkchannel(imgPatch / A)
    k_cmin2<<<grid, blk, 0, stream>>>(x, Ap3, bufA);
    k_rowmin7<<<grid, blk, 0, stream>>>(bufA, bufB);
    k_colmin7<<<grid, blk, 0, stream>>>(bufB, pb, 1);

    // guided filter (r=15, eps=1e-3)
    k_rowsum4<<<grid, blk, 0, stream>>>(Ib, pb, rs);
    k_colsum_ab<<<grid, blk, 0, stream>>>(rs, bufA, bufB);
    k_rowsum2<<<grid, blk, 0, stream>>>(bufA, bufB, bufC, pb);
    k_final<<<grid, blk, 0, stream>>>(bufC, pb, Ib, x, mapA3, out);
}

// Round 3
// 353.875 us; speedup vs baseline: 3.1911x; 1.5628x over previous
//
#include <hip/hip_runtime.h>
#include <stdint.h>

#define BB 16
#define HH 512
#define WW 512
#define HW 262144            // 2^18
#define BHW 4194304          // 16 * 2^18
#define KSEL 262
#define CAP 8192
#define NTHREADS 256
#define NBLK (BHW / NTHREADS)
#define BLKPB 64             // radix blocks per batch
#define CHUNK (HW / BLKPB)   // 4096 pixels per radix block

// ---------- helpers (rn intrinsics to suppress fma contraction in selection-critical math) ----------
__device__ __forceinline__ float img01(float xv) {
    return __fmul_rn(__fadd_rn(xv, 1.0f), 0.5f);
}
__device__ __forceinline__ float luma3(float c0, float c1, float c2) {
    float t = __fadd_rn(__fmul_rn(0.2989f, c0), __fmul_rn(0.587f, c1));
    return __fadd_rn(t, __fmul_rn(0.114f, c2));
}

// ============ dark channel row pass (fused prep): x -> Ib (guidance), rm (row min of cmin) ============
__global__ void k_dc_row(const float* __restrict__ x, float* __restrict__ Ib, float* __restrict__ rm) {
    int bid = blockIdx.x;              // 16*512
    int b = bid >> 9, y = bid & 511;
    int t = threadIdx.x;
    __shared__ float lcm[528];         // logical [-8, 519], offset 8, pad = 1.0
    const float* xb = x + (size_t)b * 3 * HW + (size_t)y * WW;
    size_t obase = (size_t)b * HW + (size_t)y * WW;
    for (int xx = t; xx < 512; xx += 256) {
        float x0 = xb[xx], x1 = xb[HW + xx], x2 = xb[2 * HW + xx];
        float i0 = img01(x0), i1 = img01(x1), i2 = img01(x2);
        lcm[8 + xx] = fminf(i0, fminf(i1, i2));
        float tt = luma3(x0, x1, x2);
        Ib[obase + xx] = __fmul_rn(__fadd_rn(tt, 1.0f), 0.5f);
    }
    if (t < 16) lcm[(t < 8) ? t : (512 + t)] = 1.0f;
    __syncthreads();
    for (int xx = t; xx < 512; xx += 256) {
        float m = lcm[8 + xx - 7];
        #pragma unroll
        for (int k = -6; k <= 7; ++k) m = fminf(m, lcm[8 + xx + k]);
        rm[obase + xx] = m;
    }
}

// ============ second dark channel row pass (fused cmin2): x, Ap3 -> rm ============
__global__ void k_dc2_row(const float* __restrict__ x, const float* __restrict__ Ap3,
                          float* __restrict__ rm) {
    int bid = blockIdx.x;
    int b = bid >> 9, y = bid & 511;
    int t = threadIdx.x;
    __shared__ float lcm[528];
    const float* xb = x + (size_t)b * 3 * HW + (size_t)y * WW;
    float a0 = Ap3[b * 3 + 0], a1 = Ap3[b * 3 + 1], a2 = Ap3[b * 3 + 2];
    size_t obase = (size_t)b * HW + (size_t)y * WW;
    for (int xx = t; xx < 512; xx += 256) {
        float v0 = __fdiv_rn(img01(xb[xx]), a0);
        float v1 = __fdiv_rn(img01(xb[HW + xx]), a1);
        float v2 = __fdiv_rn(img01(xb[2 * HW + xx]), a2);
        lcm[8 + xx] = fminf(v0, fminf(v1, v2));
    }
    if (t < 16) lcm[(t < 8) ? t : (512 + t)] = 1.0f;
    __syncthreads();
    for (int xx = t; xx < 512; xx += 256) {
        float m = lcm[8 + xx - 7];
        #pragma unroll
        for (int k = -6; k <= 7; ++k) m = fminf(m, lcm[8 + xx + k]);
        rm[obase + xx] = m;
    }
}

// ============ col min pass via LDS tile: rm -> dc (MODE 0) or trans_raw (MODE 1) ============
template <int MODE>
__global__ void k_dc_col(const float* __restrict__ in, float* __restrict__ out) {
    // grid 16*4*8; tile 128 cols x (64+14) rows
    int bid = blockIdx.x;
    int b = bid >> 5, cg = (bid >> 3) & 3, seg = bid & 7;
    int c0 = cg * 128, y0 = seg * 64;
    int t = threadIdx.x;
    __shared__ float tile[78 * 128];
    const float* ib = in + (size_t)b * HW;
    for (int i = t; i < 78 * 128; i += 256) {
        int rr = i >> 7, cc = i & 127;
        int gy = y0 - 7 + rr;
        tile[i] = (gy >= 0 && gy < 512) ? ib[(size_t)gy * WW + c0 + cc] : 1.0f;
    }
    __syncthreads();
    int col = t & 127;
    int rbase = (t >> 7) * 32;
    size_t obase = (size_t)b * HW + c0 + col;
    for (int rr = rbase; rr < rbase + 32; ++rr) {
        float m = tile[rr * 128 + col];
        #pragma unroll
        for (int k = 1; k < 15; ++k) m = fminf(m, tile[(rr + k) * 128 + col]);
        float v = (MODE == 1) ? __fsub_rn(1.0f, __fmul_rn(0.95f, m)) : m;
        out[obase + (size_t)(y0 + rr) * WW] = v;
    }
}

// ============ exact top-k via 4x8-bit radix select ============
__global__ void k_init(uint2* __restrict__ state, uint32_t* __restrict__ hist256,
                       uint32_t* __restrict__ tiecnt, unsigned long long* __restrict__ gt) {
    int t = blockIdx.x * 256 + threadIdx.x;
    if (t < 16 * 256) hist256[t] = 0;
    if (t < 16) {
        state[t] = make_uint2(0u, KSEL);
        tiecnt[t] = 0;
        gt[t] = 0ull;
    }
}

__global__ void k_radix_pass(const float* __restrict__ dc, const uint2* __restrict__ state,
                             uint32_t* __restrict__ hist256, int shift) {
    __shared__ uint32_t h[256];
    int b = blockIdx.x / BLKPB;
    int blk = blockIdx.x % BLKPB;
    h[threadIdx.x] = 0;
    __syncthreads();
    uint32_t pref = state[b].x;
    uint32_t maskhi = (shift == 24) ? 0u : (0xFFFFFFFFu << (shift + 8));
    const float4* d4 = (const float4*)(dc + (size_t)b * HW + blk * CHUNK);
    #pragma unroll
    for (int it = 0; it < CHUNK / 1024; ++it) {
        float4 v = d4[it * 256 + threadIdx.x];
        uint32_t u;
        u = __float_as_uint(v.x); if ((u & maskhi) == pref) atomicAdd(&h[(u >> shift) & 0xFFu], 1u);
        u = __float_as_uint(v.y); if ((u & maskhi) == pref) atomicAdd(&h[(u >> shift) & 0xFFu], 1u);
        u = __float_as_uint(v.z); if ((u & maskhi) == pref) atomicAdd(&h[(u >> shift) & 0xFFu], 1u);
        u = __float_as_uint(v.w); if ((u & maskhi) == pref) atomicAdd(&h[(u >> shift) & 0xFFu], 1u);
    }
    __syncthreads();
    uint32_t c = h[threadIdx.x];
    if (c) atomicAdd(&hist256[b * 256 + threadIdx.x], c);
}

__global__ void k_radix_scan(uint32_t* __restrict__ hist256, uint2* __restrict__ state, int shift) {
    int b = blockIdx.x, t = threadIdx.x;
    __shared__ uint32_t h[256];
    h[t] = hist256[b * 256 + t];
    __syncthreads();
    hist256[b * 256 + t] = 0;   // ready for next pass
    if (t == 0) {
        uint32_t target = state[b].y;
        uint32_t cum = 0, digit = 0;
        for (int i = 255; i >= 0; --i) {
            uint32_t c = h[i];
            if (cum + c >= target) { digit = (uint32_t)i; target -= cum; break; }
            cum += c;
        }
        state[b].x |= digit << shift;
        state[b].y = target;
    }
}

// ============ collect: best of strict-greater set (packed atomicMax), gather ties ============
__global__ void k_collect(const float* __restrict__ dc, const float* __restrict__ x,
                          const uint2* __restrict__ state, unsigned long long* __restrict__ gt,
                          uint32_t* __restrict__ tiecnt, uint32_t* __restrict__ ties) {
    int idx = blockIdx.x * NTHREADS + threadIdx.x;
    if (idx >= BHW) return;
    int b = idx >> 18;
    int rem = idx & (HW - 1);
    uint32_t u = __float_as_uint(dc[idx]);
    uint32_t v = state[b].x;
    if (u < v) return;
    if (u > v) {
        const float* xb = x + (size_t)b * 3 * HW + rem;
        float i0 = img01(xb[0]), i1 = img01(xb[HW]), i2 = img01(xb[2 * HW]);
        float inten = luma3(i0, i1, i2);
        unsigned long long packed =
            ((unsigned long long)__float_as_uint(inten) << 32) | (uint32_t)(0xFFFFFFFFu - (uint32_t)rem);
        atomicMax(&gt[b], packed);
    } else {
        uint32_t pos = atomicAdd(&tiecnt[b], 1u);
        if (pos < CAP) ties[(size_t)b * CAP + pos] = (uint32_t)rem;
    }
}

// ============ select: rank ties by index, take r smallest, argmax intensity; produce A ============
__global__ void k_select(const float* __restrict__ x, const uint2* __restrict__ state,
                         const unsigned long long* __restrict__ gt, const uint32_t* __restrict__ tiecnt,
                         const uint32_t* __restrict__ ties, float* __restrict__ mapA3,
                         float* __restrict__ Ap3) {
    int b = blockIdx.x, t = threadIdx.x;
    __shared__ uint32_t tl[CAP];
    __shared__ unsigned long long red[256];
    uint32_t n = tiecnt[b];
    if (n > CAP) n = CAP;
    uint32_t r = state[b].y;
    const uint32_t* tb = ties + (size_t)b * CAP;
    for (uint32_t i = t; i < n; i += 256) tl[i] = tb[i];
    __syncthreads();
    unsigned long long best = 0;
    for (uint32_t i = t; i < n; i += 256) {
        uint32_t myidx = tl[i];
        uint32_t rank = 0;
        for (uint32_t j = 0; j < n; ++j) rank += (tl[j] < myidx) ? 1u : 0u;
        if (rank < r) {
            const float* xb = x + (size_t)b * 3 * HW + myidx;
            float i0 = img01(xb[0]), i1 = img01(xb[HW]), i2 = img01(xb[2 * HW]);
            float inten = luma3(i0, i1, i2);
            unsigned long long packed =
                ((unsigned long long)__float_as_uint(inten) << 32) | (uint32_t)(0xFFFFFFFFu - myidx);
            if (packed > best) best = packed;
        }
    }
    red[t] = best;
    __syncthreads();
    for (int s2 = 128; s2 > 0; s2 >>= 1) {
        if (t < s2) red[t] = (red[t] > red[t + s2]) ? red[t] : red[t + s2];
        __syncthreads();
    }
    if (t == 0) {
        unsigned long long tie = red[0], g = gt[b];
        unsigned long long fin = ((g >> 32) >= (tie >> 32)) ? g : tie;
        if (g == 0ull) fin = tie;
        uint32_t rem = 0xFFFFFFFFu - (uint32_t)(fin & 0xFFFFFFFFull);
        const float* xb = x + (size_t)b * 3 * HW + rem;
        for (int c = 0; c < 3; ++c) {
            float A = img01(xb[c * HW]);
            float mA = __fsub_rn(__fmul_rn(A, 2.0f), 1.0f);
            float Ap = __fmul_rn(__fadd_rn(mA, 1.0f), 0.5f);
            mapA3[b * 3 + c] = mA;
            Ap3[b * 3 + c] = Ap;
        }
    }
}

// ============ guided filter row pass 1: I,p -> row sums of {I,p,Ip,II} (float2 stores) ============
__global__ void k_gf_row1(const float* __restrict__ Ib, const float* __restrict__ pb,
                          float* __restrict__ rs) {
    int bid = blockIdx.x;              // 16*512
    int b = bid >> 9, y = bid & 511;
    int t = threadIdx.x;
    __shared__ float LI[544], LP[544]; // logical [-16, 527], offset 16, pad = 0
    size_t base = (size_t)b * HW + (size_t)y * WW;
    for (int xx = t; xx < 512; xx += 256) {
        LI[16 + xx] = Ib[base + xx];
        LP[16 + xx] = pb[base + xx];
    }
    if (t < 32) {
        int i = (t < 16) ? t : (512 + t);
        LI[i] = 0.f; LP[i] = 0.f;
    }
    __syncthreads();
    int xx = 2 * t;
    float sI = 0.f, sP = 0.f, sIP = 0.f, sII = 0.f;
    #pragma unroll
    for (int k = -15; k <= 15; ++k) {
        float iv = LI[16 + xx + k], pv = LP[16 + xx + k];
        sI += iv; sP += pv; sIP += iv * pv; sII += iv * iv;
    }
    float sI0 = sI, sP0 = sP, sIP0 = sIP, sII0 = sII;
    float ivn = LI[16 + xx + 16], pvn = LP[16 + xx + 16];
    float ivo = LI[16 + xx - 15], pvo = LP[16 + xx - 15];
    sI += ivn - ivo; sP += pvn - pvo;
    sIP += ivn * pvn - ivo * pvo; sII += ivn * ivn - ivo * ivo;
    float2* r0 = (float2*)(rs + base + xx);
    float2* r1 = (float2*)(rs + (size_t)BHW + base + xx);
    float2* r2 = (float2*)(rs + (size_t)2 * BHW + base + xx);
    float2* r3 = (float2*)(rs + (size_t)3 * BHW + base + xx);
    *r0 = make_float2(sI0, sI);
    *r1 = make_float2(sP0, sP);
    *r2 = make_float2(sIP0, sIP);
    *r3 = make_float2(sII0, sII);
}

// ============ guided filter col pass + a,b: running column sums of 4 planes ============
__global__ void k_gf_colab(const float* __restrict__ rs, float* __restrict__ aout,
                           float* __restrict__ bout) {
    // grid 16*2*8, thread-per-column, 64-row segments
    int bid = blockIdx.x;
    int b = bid >> 4, cg = (bid >> 3) & 1, seg = bid & 7;
    int col = cg * 256 + threadIdx.x;
    int y0 = seg * 64;
    const float* rI = rs;
    const float* rP = rs + (size_t)BHW;
    const float* rIP = rs + (size_t)2 * BHW;
    const float* rII = rs + (size_t)3 * BHW;
    size_t pc = (size_t)b * HW + col;
    float sI = 0.f, sP = 0.f, sIP = 0.f, sII = 0.f;
    for (int yy = y0 - 15; yy <= y0 + 15; ++yy) {
        if (yy >= 0 && yy < 512) {
            size_t o = pc + (size_t)yy * WW;
            sI += rI[o]; sP += rP[o]; sIP += rIP[o]; sII += rII[o];
        }
    }
    int nx = min(511, col + 15) - max(0, col - 15) + 1;
    for (int j = 0; j < 64; ++j) {
        int y = y0 + j;
        if (j > 0) {
            int ya = y + 15, yr = y - 16;
            if (ya < 512) {
                size_t o = pc + (size_t)ya * WW;
                sI += rI[o]; sP += rP[o]; sIP += rIP[o]; sII += rII[o];
            }
            if (yr >= 0) {
                size_t o = pc + (size_t)yr * WW;
                sI -= rI[o]; sP -= rP[o]; sIP -= rIP[o]; sII -= rII[o];
            }
        }
        int ny = min(511, y + 15) - max(0, y - 15) + 1;
        float N = (float)(ny * nx);
        float mI = sI / N, mP = sP / N, mIP = sIP / N, mII = sII / N;
        float cov = mIP - mI * mP;
        float var = mII - mI * mI;
        float a = cov / (var + 1e-3f);
        float bb = mP - a * mI;
        size_t o = pc + (size_t)y * WW;
        aout[o] = a;
        bout[o] = bb;
    }
}

// ============ guided filter row pass 2: a,b -> row sums ra,rb ============
__global__ void k_gf_row2(const float* __restrict__ a, const float* __restrict__ bpl,
                          float* __restrict__ ra, float* __restrict__ rb) {
    int bid = blockIdx.x;
    int b = bid >> 9, y = bid & 511;
    int t = threadIdx.x;
    __shared__ float LA[544], LB[544];
    size_t base = (size_t)b * HW + (size_t)y * WW;
    for (int xx = t; xx < 512; xx += 256) {
        LA[16 + xx] = a[base + xx];
        LB[16 + xx] = bpl[base + xx];
    }
    if (t < 32) {
        int i = (t < 16) ? t : (512 + t);
        LA[i] = 0.f; LB[i] = 0.f;
    }
    __syncthreads();
    int xx = 2 * t;
    float sa = 0.f, sb = 0.f;
    #pragma unroll
    for (int k = -15; k <= 15; ++k) {
        sa += LA[16 + xx + k];
        sb += LB[16 + xx + k];
    }
    float sa0 = sa, sb0 = sb;
    sa += LA[16 + xx + 16] - LA[16 + xx - 15];
    sb += LB[16 + xx + 16] - LB[16 + xx - 15];
    *(float2*)(ra + base + xx) = make_float2(sa0, sa);
    *(float2*)(rb + base + xx) = make_float2(sb0, sb);
}

// ============ final: running column sums of ra,rb -> T, J, mapA ============
__global__ void k_final_col(const float* __restrict__ ra, const float* __restrict__ rb,
                            const float* __restrict__ Ib, const float* __restrict__ x,
                            const float* __restrict__ mapA3, float* __restrict__ out) {
    int bid = blockIdx.x;
    int b = bid >> 4, cg = (bid >> 3) & 1, seg = bid & 7;
    int col = cg * 256 + threadIdx.x;
    int y0 = seg * 64;
    size_t pc = (size_t)b * HW + col;
    float mA0 = mapA3[b * 3 + 0], mA1 = mapA3[b * 3 + 1], mA2 = mapA3[b * 3 + 2];
    const float* x0p = x + (size_t)b * 3 * HW + col;
    float Sa = 0.f, Sb = 0.f;
    for (int yy = y0 - 15; yy <= y0 + 15; ++yy) {
        if (yy >= 0 && yy < 512) {
            size_t o = pc + (size_t)yy * WW;
            Sa += ra[o]; Sb += rb[o];
        }
    }
    int nx = min(511, col + 15) - max(0, col - 15) + 1;
    for (int j = 0; j < 64; ++j) {
        int y = y0 + j;
        if (j > 0) {
            int ya = y + 15, yr = y - 16;
            if (ya < 512) {
                size_t o = pc + (size_t)ya * WW;
                Sa += ra[o]; Sb += rb[o];
            }
            if (yr >= 0) {
                size_t o = pc + (size_t)yr * WW;
                Sa -= ra[o]; Sb -= rb[o];
            }
        }
        int ny = min(511, y + 15) - max(0, y - 15) + 1;
        float N = (float)(ny * nx);
        float ma = Sa / N, mb = Sb / N;
        size_t yo = (size_t)y * WW;
        float Iv = Ib[pc + yo];
        float T = ma * Iv + mb;
        out[(size_t)3 * BHW + pc + yo] = T;
        float i0 = img01(x0p[yo]);
        float i1 = img01(x0p[(size_t)HW + yo]);
        float i2 = img01(x0p[(size_t)2 * HW + yo]);
        size_t j0 = (size_t)(b * 3) * HW + yo + col;
        out[j0] = (i0 - mA0) / T + mA0;
        out[j0 + HW] = (i1 - mA1) / T + mA1;
        out[j0 + 2 * HW] = (i2 - mA2) / T + mA2;
        out[(size_t)4 * BHW + j0] = mA0;
        out[(size_t)4 * BHW + j0 + HW] = mA1;
        out[(size_t)4 * BHW + j0 + 2 * HW] = mA2;
    }
}

extern "C" void kernel_launch(void* const* d_in, const int* in_sizes, int n_in,
                              void* d_out, int out_size, void* d_ws, size_t ws_size,
                              hipStream_t stream) {
    const float* x = (const float*)d_in[0];
    float* out = (float*)d_out;
    char* ws = (char*)d_ws;

    // ws planes
    float* Ib = (float*)ws;                    // guidance
    float* rm = Ib + (size_t)BHW;              // row-min tmp; later ra
    float* dc = Ib + (size_t)2 * BHW;          // dark channel; later rb
    float* pb = Ib + (size_t)3 * BHW;          // trans_raw
    char* small = ws + (size_t)4 * BHW * 4;
    uint2* state = (uint2*)(small + 0);
    uint32_t* tiecnt = (uint32_t*)(small + 256);
    unsigned long long* gt = (unsigned long long*)(small + 384);
    float* mapA3 = (float*)(small + 512);
    float* Ap3 = (float*)(small + 768);
    uint32_t* hist256 = (uint32_t*)(small + 1024);              // 16 KB
    uint32_t* ties = (uint32_t*)(small + 1024 + 16 * 256 * 4);  // 512 KB
    // d_out reuse: rs4 = out planes 0..3, a = plane 4, b = plane 5 (consumed before final writes)
    float* rs = out;
    float* apl = out + (size_t)4 * BHW;
    float* bpl = out + (size_t)5 * BHW;
    float* ra = rm;
    float* rb = dc;

    // dark channel of imgPatch (bit-exact min path)
    k_dc_row<<<16 * 512, 256, 0, stream>>>(x, Ib, rm);
    k_dc_col<0><<<16 * 4 * 8, 256, 0, stream>>>(rm, dc);

    // exact top-k: k-th largest dc value + tie count, 4x8-bit radix select
    k_init<<<16, 256, 0, stream>>>(state, hist256, tiecnt, gt);
    for (int shift = 24; shift >= 0; shift -= 8) {
        k_radix_pass<<<16 * BLKPB, 256, 0, stream>>>(dc, state, hist256, shift);
        k_radix_scan<<<16, 256, 0, stream>>>(hist256, state, shift);
    }
    k_collect<<<NBLK, NTHREADS, 0, stream>>>(dc, x, state, gt, tiecnt, ties);
    k_select<<<16, 256, 0, stream>>>(x, state, gt, tiecnt, ties, mapA3, Ap3);

    // trans_raw = 1 - 0.95 * darkchannel(imgPatch / A)
    k_dc2_row<<<16 * 512, 256, 0, stream>>>(x, Ap3, rm);
    k_dc_col<1><<<16 * 4 * 8, 256, 0, stream>>>(rm, pb);

    // guided filter (r=15, eps=1e-3)
    k_gf_row1<<<16 * 512, 256, 0, stream>>>(Ib, pb, rs);
    k_gf_colab<<<16 * 2 * 8, 256, 0, stream>>>(rs, apl, bpl);
    k_gf_row2<<<16 * 512, 256, 0, stream>>>(apl, bpl, ra, rb);
    k_final_col<<<16 * 2 * 8, 256, 0, stream>>>(ra, rb, Ib, x, mapA3, out);
}

// Round 4
// 303.812 us; speedup vs baseline: 3.7169x; 1.1648x over previous
//
#include <hip/hip_runtime.h>
#include <stdint.h>

#define BB 16
#define HH 512
#define WW 512
#define HW 262144            // 2^18
#define BHW 4194304          // 16 * 2^18
#define KSEL 262
#define CAP 8192
#define NTHREADS 256
#define NBLK (BHW / NTHREADS)
#define BLKPB 64             // radix blocks per batch
#define CHUNK (HW / BLKPB)   // 4096 pixels per radix block

// ---------- helpers (rn intrinsics to suppress fma contraction in selection-critical math) ----------
__device__ __forceinline__ float img01(float xv) {
    return __fmul_rn(__fadd_rn(xv, 1.0f), 0.5f);
}
__device__ __forceinline__ float luma3(float c0, float c1, float c2) {
    float t = __fadd_rn(__fmul_rn(0.2989f, c0), __fmul_rn(0.587f, c1));
    return __fadd_rn(t, __fmul_rn(0.114f, c2));
}

// ============ dark channel row pass (fused prep + radix-state init) ============
__global__ void k_dc_row(const float* __restrict__ x, float* __restrict__ Ib, float* __restrict__ rm,
                         uint2* __restrict__ state, uint32_t* __restrict__ hist256,
                         uint32_t* __restrict__ tiecnt, unsigned long long* __restrict__ gt) {
    int bid = blockIdx.x;              // 16*512
    int b = bid >> 9, y = bid & 511;
    int t = threadIdx.x;
    // fold k_init into the first 16 blocks (runs well before any radix kernel)
    if (bid < 16) {
        hist256[bid * 256 + t] = 0;
        if (t == 0) {
            state[bid] = make_uint2(0u, KSEL);
            tiecnt[bid] = 0;
            gt[bid] = 0ull;
        }
    }
    __shared__ float lcm[528];         // logical [-8, 519], offset 8, pad = 1.0
    const float* xb = x + (size_t)b * 3 * HW + (size_t)y * WW;
    size_t obase = (size_t)b * HW + (size_t)y * WW;
    for (int xx = t; xx < 512; xx += 256) {
        float x0 = xb[xx], x1 = xb[HW + xx], x2 = xb[2 * HW + xx];
        float i0 = img01(x0), i1 = img01(x1), i2 = img01(x2);
        lcm[8 + xx] = fminf(i0, fminf(i1, i2));
        float tt = luma3(x0, x1, x2);
        Ib[obase + xx] = __fmul_rn(__fadd_rn(tt, 1.0f), 0.5f);
    }
    if (t < 16) lcm[(t < 8) ? t : (512 + t)] = 1.0f;
    __syncthreads();
    for (int xx = t; xx < 512; xx += 256) {
        float m = lcm[8 + xx - 7];
        #pragma unroll
        for (int k = -6; k <= 7; ++k) m = fminf(m, lcm[8 + xx + k]);
        rm[obase + xx] = m;
    }
}

// ============ second dark channel row pass (fused cmin2): x, Ap3 -> rm ============
__global__ void k_dc2_row(const float* __restrict__ x, const float* __restrict__ Ap3,
                          float* __restrict__ rm) {
    int bid = blockIdx.x;
    int b = bid >> 9, y = bid & 511;
    int t = threadIdx.x;
    __shared__ float lcm[528];
    const float* xb = x + (size_t)b * 3 * HW + (size_t)y * WW;
    float a0 = Ap3[b * 3 + 0], a1 = Ap3[b * 3 + 1], a2 = Ap3[b * 3 + 2];
    size_t obase = (size_t)b * HW + (size_t)y * WW;
    for (int xx = t; xx < 512; xx += 256) {
        float v0 = __fdiv_rn(img01(xb[xx]), a0);
        float v1 = __fdiv_rn(img01(xb[HW + xx]), a1);
        float v2 = __fdiv_rn(img01(xb[2 * HW + xx]), a2);
        lcm[8 + xx] = fminf(v0, fminf(v1, v2));
    }
    if (t < 16) lcm[(t < 8) ? t : (512 + t)] = 1.0f;
    __syncthreads();
    for (int xx = t; xx < 512; xx += 256) {
        float m = lcm[8 + xx - 7];
        #pragma unroll
        for (int k = -6; k <= 7; ++k) m = fminf(m, lcm[8 + xx + k]);
        rm[obase + xx] = m;
    }
}

// ============ col min pass via LDS tile: rm -> dc (MODE 0) or trans_raw (MODE 1) ============
template <int MODE>
__global__ void k_dc_col(const float* __restrict__ in, float* __restrict__ out) {
    // grid 16*4*8; tile 128 cols x (64+14) rows
    int bid = blockIdx.x;
    int b = bid >> 5, cg = (bid >> 3) & 3, seg = bid & 7;
    int c0 = cg * 128, y0 = seg * 64;
    int t = threadIdx.x;
    __shared__ float tile[78 * 128];
    const float* ib = in + (size_t)b * HW;
    for (int i = t; i < 78 * 128; i += 256) {
        int rr = i >> 7, cc = i & 127;
        int gy = y0 - 7 + rr;
        tile[i] = (gy >= 0 && gy < 512) ? ib[(size_t)gy * WW + c0 + cc] : 1.0f;
    }
    __syncthreads();
    int col = t & 127;
    int rbase = (t >> 7) * 32;
    size_t obase = (size_t)b * HW + c0 + col;
    for (int rr = rbase; rr < rbase + 32; ++rr) {
        float m = tile[rr * 128 + col];
        #pragma unroll
        for (int k = 1; k < 15; ++k) m = fminf(m, tile[(rr + k) * 128 + col]);
        float v = (MODE == 1) ? __fsub_rn(1.0f, __fmul_rn(0.95f, m)) : m;
        out[obase + (size_t)(y0 + rr) * WW] = v;
    }
}

// ============ exact top-k via 4x8-bit radix select ============
__global__ void k_radix_pass(const float* __restrict__ dc, const uint2* __restrict__ state,
                             uint32_t* __restrict__ hist256, int shift) {
    __shared__ uint32_t h[256];
    int b = blockIdx.x / BLKPB;
    int blk = blockIdx.x % BLKPB;
    h[threadIdx.x] = 0;
    __syncthreads();
    uint32_t pref = state[b].x;
    uint32_t maskhi = (shift == 24) ? 0u : (0xFFFFFFFFu << (shift + 8));
    const float4* d4 = (const float4*)(dc + (size_t)b * HW + blk * CHUNK);
    #pragma unroll
    for (int it = 0; it < CHUNK / 1024; ++it) {
        float4 v = d4[it * 256 + threadIdx.x];
        uint32_t u;
        u = __float_as_uint(v.x); if ((u & maskhi) == pref) atomicAdd(&h[(u >> shift) & 0xFFu], 1u);
        u = __float_as_uint(v.y); if ((u & maskhi) == pref) atomicAdd(&h[(u >> shift) & 0xFFu], 1u);
        u = __float_as_uint(v.z); if ((u & maskhi) == pref) atomicAdd(&h[(u >> shift) & 0xFFu], 1u);
        u = __float_as_uint(v.w); if ((u & maskhi) == pref) atomicAdd(&h[(u >> shift) & 0xFFu], 1u);
    }
    __syncthreads();
    uint32_t c = h[threadIdx.x];
    if (c) atomicAdd(&hist256[b * 256 + threadIdx.x], c);
}

__global__ void k_radix_scan(uint32_t* __restrict__ hist256, uint2* __restrict__ state, int shift) {
    int b = blockIdx.x, t = threadIdx.x;
    __shared__ uint32_t h[256];
    h[t] = hist256[b * 256 + t];
    __syncthreads();
    hist256[b * 256 + t] = 0;   // ready for next pass
    if (t == 0) {
        uint32_t target = state[b].y;
        uint32_t cum = 0, digit = 0;
        for (int i = 255; i >= 0; --i) {
            uint32_t c = h[i];
            if (cum + c >= target) { digit = (uint32_t)i; target -= cum; break; }
            cum += c;
        }
        state[b].x |= digit << shift;
        state[b].y = target;
    }
}

// ============ collect: best of strict-greater set (packed atomicMax), gather ties ============
__global__ void k_collect(const float* __restrict__ dc, const float* __restrict__ x,
                          const uint2* __restrict__ state, unsigned long long* __restrict__ gt,
                          uint32_t* __restrict__ tiecnt, uint32_t* __restrict__ ties) {
    int idx = blockIdx.x * NTHREADS + threadIdx.x;
    if (idx >= BHW) return;
    int b = idx >> 18;
    int rem = idx & (HW - 1);
    uint32_t u = __float_as_uint(dc[idx]);
    uint32_t v = state[b].x;
    if (u < v) return;
    if (u > v) {
        const float* xb = x + (size_t)b * 3 * HW + rem;
        float i0 = img01(xb[0]), i1 = img01(xb[HW]), i2 = img01(xb[2 * HW]);
        float inten = luma3(i0, i1, i2);
        unsigned long long packed =
            ((unsigned long long)__float_as_uint(inten) << 32) | (uint32_t)(0xFFFFFFFFu - (uint32_t)rem);
        atomicMax(&gt[b], packed);
    } else {
        uint32_t pos = atomicAdd(&tiecnt[b], 1u);
        if (pos < CAP) ties[(size_t)b * CAP + pos] = (uint32_t)rem;
    }
}

// ============ select: rank ties by index, take r smallest, argmax intensity; produce A ============
__global__ void k_select(const float* __restrict__ x, const uint2* __restrict__ state,
                         const unsigned long long* __restrict__ gt, const uint32_t* __restrict__ tiecnt,
                         const uint32_t* __restrict__ ties, float* __restrict__ mapA3,
                         float* __restrict__ Ap3) {
    int b = blockIdx.x, t = threadIdx.x;
    __shared__ uint32_t tl[CAP];
    __shared__ unsigned long long red[256];
    uint32_t n = tiecnt[b];
    if (n > CAP) n = CAP;
    uint32_t r = state[b].y;
    const uint32_t* tb = ties + (size_t)b * CAP;
    for (uint32_t i = t; i < n; i += 256) tl[i] = tb[i];
    __syncthreads();
    unsigned long long best = 0;
    for (uint32_t i = t; i < n; i += 256) {
        uint32_t myidx = tl[i];
        uint32_t rank = 0;
        for (uint32_t j = 0; j < n; ++j) rank += (tl[j] < myidx) ? 1u : 0u;
        if (rank < r) {
            const float* xb = x + (size_t)b * 3 * HW + myidx;
            float i0 = img01(xb[0]), i1 = img01(xb[HW]), i2 = img01(xb[2 * HW]);
            float inten = luma3(i0, i1, i2);
            unsigned long long packed =
                ((unsigned long long)__float_as_uint(inten) << 32) | (uint32_t)(0xFFFFFFFFu - myidx);
            if (packed > best) best = packed;
        }
    }
    red[t] = best;
    __syncthreads();
    for (int s2 = 128; s2 > 0; s2 >>= 1) {
        if (t < s2) red[t] = (red[t] > red[t + s2]) ? red[t] : red[t + s2];
        __syncthreads();
    }
    if (t == 0) {
        unsigned long long tie = red[0], g = gt[b];
        unsigned long long fin = ((g >> 32) >= (tie >> 32)) ? g : tie;
        if (g == 0ull) fin = tie;
        uint32_t rem = 0xFFFFFFFFu - (uint32_t)(fin & 0xFFFFFFFFull);
        const float* xb = x + (size_t)b * 3 * HW + rem;
        for (int c = 0; c < 3; ++c) {
            float A = img01(xb[c * HW]);
            float mA = __fsub_rn(__fmul_rn(A, 2.0f), 1.0f);
            float Ap = __fmul_rn(__fadd_rn(mA, 1.0f), 0.5f);
            mapA3[b * 3 + c] = mA;
            Ap3[b * 3 + c] = Ap;
        }
    }
}

// ============ guided filter row pass 1: I,p -> row sums of {I,p,Ip,II} (float2 stores) ============
__global__ void k_gf_row1(const float* __restrict__ Ib, const float* __restrict__ pb,
                          float* __restrict__ rs) {
    int bid = blockIdx.x;              // 16*512
    int b = bid >> 9, y = bid & 511;
    int t = threadIdx.x;
    __shared__ float LI[544], LP[544]; // logical [-16, 527], offset 16, pad = 0
    size_t base = (size_t)b * HW + (size_t)y * WW;
    for (int xx = t; xx < 512; xx += 256) {
        LI[16 + xx] = Ib[base + xx];
        LP[16 + xx] = pb[base + xx];
    }
    if (t < 32) {
        int i = (t < 16) ? t : (512 + t);
        LI[i] = 0.f; LP[i] = 0.f;
    }
    __syncthreads();
    int xx = 2 * t;
    float sI = 0.f, sP = 0.f, sIP = 0.f, sII = 0.f;
    #pragma unroll
    for (int k = -15; k <= 15; ++k) {
        float iv = LI[16 + xx + k], pv = LP[16 + xx + k];
        sI += iv; sP += pv; sIP += iv * pv; sII += iv * iv;
    }
    float sI0 = sI, sP0 = sP, sIP0 = sIP, sII0 = sII;
    float ivn = LI[16 + xx + 16], pvn = LP[16 + xx + 16];
    float ivo = LI[16 + xx - 15], pvo = LP[16 + xx - 15];
    sI += ivn - ivo; sP += pvn - pvo;
    sIP += ivn * pvn - ivo * pvo; sII += ivn * ivn - ivo * ivo;
    float2* r0 = (float2*)(rs + base + xx);
    float2* r1 = (float2*)(rs + (size_t)BHW + base + xx);
    float2* r2 = (float2*)(rs + (size_t)2 * BHW + base + xx);
    float2* r3 = (float2*)(rs + (size_t)3 * BHW + base + xx);
    *r0 = make_float2(sI0, sI);
    *r1 = make_float2(sP0, sP);
    *r2 = make_float2(sIP0, sIP);
    *r3 = make_float2(sII0, sII);
}

// ============ guided filter col pass + a,b: running column sums, 16-row segments ============
__global__ void k_gf_colab(const float* __restrict__ rs, float* __restrict__ aout,
                           float* __restrict__ bout) {
    // grid 16*2*32, thread-per-column, 16-row segments (4 blocks/CU -> 16 waves/CU)
    int bid = blockIdx.x;
    int b = bid >> 6, cg = (bid >> 5) & 1, seg = bid & 31;
    int col = cg * 256 + threadIdx.x;
    int y0 = seg * 16;
    const float* rI = rs;
    const float* rP = rs + (size_t)BHW;
    const float* rIP = rs + (size_t)2 * BHW;
    const float* rII = rs + (size_t)3 * BHW;
    size_t pc = (size_t)b * HW + col;
    float sI = 0.f, sP = 0.f, sIP = 0.f, sII = 0.f;
    for (int yy = y0 - 15; yy <= y0 + 15; ++yy) {
        if (yy >= 0 && yy < 512) {
            size_t o = pc + (size_t)yy * WW;
            sI += rI[o]; sP += rP[o]; sIP += rIP[o]; sII += rII[o];
        }
    }
    int nx = min(511, col + 15) - max(0, col - 15) + 1;
    for (int j = 0; j < 16; ++j) {
        int y = y0 + j;
        if (j > 0) {
            int ya = y + 15, yr = y - 16;
            if (ya < 512) {
                size_t o = pc + (size_t)ya * WW;
                sI += rI[o]; sP += rP[o]; sIP += rIP[o]; sII += rII[o];
            }
            if (yr >= 0) {
                size_t o = pc + (size_t)yr * WW;
                sI -= rI[o]; sP -= rP[o]; sIP -= rIP[o]; sII -= rII[o];
            }
        }
        int ny = min(511, y + 15) - max(0, y - 15) + 1;
        float N = (float)(ny * nx);
        float mI = sI / N, mP = sP / N, mIP = sIP / N, mII = sII / N;
        float cov = mIP - mI * mP;
        float var = mII - mI * mI;
        float a = cov / (var + 1e-3f);
        float bb = mP - a * mI;
        size_t o = pc + (size_t)y * WW;
        aout[o] = a;
        bout[o] = bb;
    }
}

// ============ guided filter row pass 2: a,b -> row sums ra,rb ============
__global__ void k_gf_row2(const float* __restrict__ a, const float* __restrict__ bpl,
                          float* __restrict__ ra, float* __restrict__ rb) {
    int bid = blockIdx.x;
    int b = bid >> 9, y = bid & 511;
    int t = threadIdx.x;
    __shared__ float LA[544], LB[544];
    size_t base = (size_t)b * HW + (size_t)y * WW;
    for (int xx = t; xx < 512; xx += 256) {
        LA[16 + xx] = a[base + xx];
        LB[16 + xx] = bpl[base + xx];
    }
    if (t < 32) {
        int i = (t < 16) ? t : (512 + t);
        LA[i] = 0.f; LB[i] = 0.f;
    }
    __syncthreads();
    int xx = 2 * t;
    float sa = 0.f, sb = 0.f;
    #pragma unroll
    for (int k = -15; k <= 15; ++k) {
        sa += LA[16 + xx + k];
        sb += LB[16 + xx + k];
    }
    float sa0 = sa, sb0 = sb;
    sa += LA[16 + xx + 16] - LA[16 + xx - 15];
    sb += LB[16 + xx + 16] - LB[16 + xx - 15];
    *(float2*)(ra + base + xx) = make_float2(sa0, sa);
    *(float2*)(rb + base + xx) = make_float2(sb0, sb);
}

// ============ final: running column sums of ra,rb -> T, J, mapA (16-row segments) ============
__global__ void k_final_col(const float* __restrict__ ra, const float* __restrict__ rb,
                            const float* __restrict__ Ib, const float* __restrict__ x,
                            const float* __restrict__ mapA3, float* __restrict__ out) {
    int bid = blockIdx.x;
    int b = bid >> 6, cg = (bid >> 5) & 1, seg = bid & 31;
    int col = cg * 256 + threadIdx.x;
    int y0 = seg * 16;
    size_t pc = (size_t)b * HW + col;
    float mA0 = mapA3[b * 3 + 0], mA1 = mapA3[b * 3 + 1], mA2 = mapA3[b * 3 + 2];
    const float* x0p = x + (size_t)b * 3 * HW + col;
    float Sa = 0.f, Sb = 0.f;
    for (int yy = y0 - 15; yy <= y0 + 15; ++yy) {
        if (yy >= 0 && yy < 512) {
            size_t o = pc + (size_t)yy * WW;
            Sa += ra[o]; Sb += rb[o];
        }
    }
    int nx = min(511, col + 15) - max(0, col - 15) + 1;
    for (int j = 0; j < 16; ++j) {
        int y = y0 + j;
        if (j > 0) {
            int ya = y + 15, yr = y - 16;
            if (ya < 512) {
                size_t o = pc + (size_t)ya * WW;
                Sa += ra[o]; Sb += rb[o];
            }
            if (yr >= 0) {
                size_t o = pc + (size_t)yr * WW;
                Sa -= ra[o]; Sb -= rb[o];
            }
        }
        int ny = min(511, y + 15) - max(0, y - 15) + 1;
        float N = (float)(ny * nx);
        float ma = Sa / N, mb = Sb / N;
        size_t yo = (size_t)y * WW;
        float Iv = Ib[pc + yo];
        float T = ma * Iv + mb;
        out[(size_t)3 * BHW + pc + yo] = T;
        float i0 = img01(x0p[yo]);
        float i1 = img01(x0p[(size_t)HW + yo]);
        float i2 = img01(x0p[(size_t)2 * HW + yo]);
        size_t j0 = (size_t)(b * 3) * HW + yo + col;
        out[j0] = (i0 - mA0) / T + mA0;
        out[j0 + HW] = (i1 - mA1) / T + mA1;
        out[j0 + 2 * HW] = (i2 - mA2) / T + mA2;
        out[(size_t)4 * BHW + j0] = mA0;
        out[(size_t)4 * BHW + j0 + HW] = mA1;
        out[(size_t)4 * BHW + j0 + 2 * HW] = mA2;
    }
}

extern "C" void kernel_launch(void* const* d_in, const int* in_sizes, int n_in,
                              void* d_out, int out_size, void* d_ws, size_t ws_size,
                              hipStream_t stream) {
    const float* x = (const float*)d_in[0];
    float* out = (float*)d_out;
    char* ws = (char*)d_ws;

    // ws planes
    float* Ib = (float*)ws;                    // guidance
    float* rm = Ib + (size_t)BHW;              // row-min tmp; later ra
    float* dc = Ib + (size_t)2 * BHW;          // dark channel; later rb
    float* pb = Ib + (size_t)3 * BHW;          // trans_raw
    char* small = ws + (size_t)4 * BHW * 4;
    uint2* state = (uint2*)(small + 0);
    uint32_t* tiecnt = (uint32_t*)(small + 256);
    unsigned long long* gt = (unsigned long long*)(small + 384);
    float* mapA3 = (float*)(small + 512);
    float* Ap3 = (float*)(small + 768);
    uint32_t* hist256 = (uint32_t*)(small + 1024);              // 16 KB
    uint32_t* ties = (uint32_t*)(small + 1024 + 16 * 256 * 4);  // 512 KB
    // d_out reuse: rs4 = out planes 0..3, a = plane 4, b = plane 5 (consumed before final writes)
    float* rs = out;
    float* apl = out + (size_t)4 * BHW;
    float* bpl = out + (size_t)5 * BHW;
    float* ra = rm;
    float* rb = dc;

    // dark channel of imgPatch (bit-exact min path) + radix-state init
    k_dc_row<<<16 * 512, 256, 0, stream>>>(x, Ib, rm, state, hist256, tiecnt, gt);
    k_dc_col<0><<<16 * 4 * 8, 256, 0, stream>>>(rm, dc);

    // exact top-k: k-th largest dc value + tie count, 4x8-bit radix select
    for (int shift = 24; shift >= 0; shift -= 8) {
        k_radix_pass<<<16 * BLKPB, 256, 0, stream>>>(dc, state, hist256, shift);
        k_radix_scan<<<16, 256, 0, stream>>>(hist256, state, shift);
    }
    k_collect<<<NBLK, NTHREADS, 0, stream>>>(dc, x, state, gt, tiecnt, ties);
    k_select<<<16, 256, 0, stream>>>(x, state, gt, tiecnt, ties, mapA3, Ap3);

    // trans_raw = 1 - 0.95 * darkchannel(imgPatch / A)
    k_dc2_row<<<16 * 512, 256, 0, stream>>>(x, Ap3, rm);
    k_dc_col<1><<<16 * 4 * 8, 256, 0, stream>>>(rm, pb);

    // guided filter (r=15, eps=1e-3)
    k_gf_row1<<<16 * 512, 256, 0, stream>>>(Ib, pb, rs);
    k_gf_colab<<<16 * 2 * 32, 256, 0, stream>>>(rs, apl, bpl);
    k_gf_row2<<<16 * 512, 256, 0, stream>>>(apl, bpl, ra, rb);
    k_final_col<<<16 * 2 * 32, 256, 0, stream>>>(ra, rb, Ib, x, mapA3, out);
}